// Round 8
// baseline (148.405 us; speedup 1.0000x reference)
//
#include <hip/hip_runtime.h>

typedef float  f32x4 __attribute__((ext_vector_type(4)));
typedef short  s16x8 __attribute__((ext_vector_type(8)));

__device__ __forceinline__ unsigned short f2bf(float f){
    unsigned int u = __float_as_uint(f);
    u = u + 0x7FFFu + ((u >> 16) & 1u);      // RNE
    return (unsigned short)(u >> 16);
}

// ---------------- K0: merged prep — bits (blocks 0..2047) + WT (blocks 2048..2303) -------
__global__ void k_prep(const float* __restrict__ W, unsigned short* __restrict__ WT,
                       const int* __restrict__ mask, unsigned long long* __restrict__ bits64){
    int bid = blockIdx.x;
    if (bid < 2048){
        int i = bid;
        int wave = threadIdx.x >> 6, lane = threadIdx.x & 63;
        for (int c = wave; c < 32; c += 4){
            int v = mask[i*2048 + c*64 + lane];
            unsigned long long b = __ballot(v != 0);
            if (lane == 0) bits64[i*32 + c] = b;
        }
    } else {
        int c = bid - 2048, k = threadIdx.x;
        WT[c*256 + k] = f2bf(W[k*256 + c]);
    }
}

// ---------------- K1: h = x @ W, fused src/dst -> E1,E2,F1,F2 (R5 structure verbatim) ----
__global__ __launch_bounds__(256) void k_gemm(const float* __restrict__ x,
        const unsigned short* __restrict__ WT,
        const float* __restrict__ a_src, const float* __restrict__ a_dst,
        unsigned short* __restrict__ hTt, float* __restrict__ E1a, float* __restrict__ E2a,
        float* __restrict__ F1a, float* __restrict__ F2a){
    const int wave = threadIdx.x >> 6, lane = threadIdx.x & 63;
    const int q = lane >> 4, t = lane & 15;
    const int m0 = blockIdx.x*64 + wave*16;   // row tile (r = b*2048+n)
    const int head = blockIdx.y;
    f32x4 acc[4] = {{0,0,0,0},{0,0,0,0},{0,0,0,0},{0,0,0,0}};
    const int row = m0 + t;
    for (int k = 0; k < 256; k += 32){
        int kk = k + q*8;
        const float* xp = x + row*256 + kk;
        f32x4 x0 = *reinterpret_cast<const f32x4*>(xp);
        f32x4 x1 = *reinterpret_cast<const f32x4*>(xp + 4);
        s16x8 a;
#pragma unroll
        for (int j = 0; j < 4; j++){ a[j] = (short)f2bf(x0[j]); a[j+4] = (short)f2bf(x1[j]); }
#pragma unroll
        for (int dblk = 0; dblk < 4; dblk++){
            s16x8 bfr = *reinterpret_cast<const s16x8*>(WT + (head*64 + dblk*16 + t)*256 + kk);
            acc[dblk] = __builtin_amdgcn_mfma_f32_16x16x32_bf16(a, bfr, acc[dblk], 0, 0, 0);
        }
    }
    const int b = m0 >> 11;                   // tile never straddles batch boundary
    const int bh = b*4 + head;
    const int jb = (m0 & 2047) >> 4;
    float as_[4], ad_[4];
#pragma unroll
    for (int dblk = 0; dblk < 4; dblk++){
        as_[dblk] = a_src[head*64 + dblk*16 + t];
        ad_[dblk] = a_dst[head*64 + dblk*16 + t];
    }
#pragma unroll
    for (int reg = 0; reg < 4; reg++){
        float sv = acc[0][reg]*as_[0] + acc[1][reg]*as_[1] + acc[2][reg]*as_[2] + acc[3][reg]*as_[3];
        float dv = acc[0][reg]*ad_[0] + acc[1][reg]*ad_[1] + acc[2][reg]*ad_[2] + acc[3][reg]*ad_[3];
#pragma unroll
        for (int off = 1; off < 16; off <<= 1){
            sv += __shfl_xor(sv, off);
            dv += __shfl_xor(dv, off);
        }
        if (t == 0){
            int n = (m0 & 2047) + q*4 + reg;
            E1a[bh*2048 + n] = __expf(sv);
            E2a[bh*2048 + n] = __expf(0.2f*sv);
            F1a[bh*2048 + n] = __expf(dv);
            F2a[bh*2048 + n] = __expf(0.2f*dv);
        }
    }
#pragma unroll
    for (int dblk = 0; dblk < 4; dblk++){
        int d = dblk*16 + t;
#pragma unroll
        for (int reg = 0; reg < 4; reg++){
            int jj = q*4 + reg;               // n = m0 + jj
            hTt[((bh*128 + jb)*64 + d)*16 + jj] = f2bf(acc[dblk][reg]);
        }
    }
}

// ---------------- K2: fused masked softmax + PV + ELU ----------------
// grid (16 bh, 32 i-tiles of 64 rows), block 256 = 4 waves, wave = 512-wide j-chunk,
// 4 A-fragments (64 i-rows) per wave; factorized exp; ones-MFMA row sums.
__device__ __forceinline__ s16x8 make_p2(unsigned int bs, float e1, float e2,
        f32x4 f1lo, f32x4 f1hi, f32x4 f2lo, f32x4 f2hi){
    float p[8];
#pragma unroll
    for (int jj = 0; jj < 8; jj++){
        float F1 = (jj < 4) ? f1lo[jj] : f1hi[jj-4];
        float F2 = (jj < 4) ? f2lo[jj] : f2hi[jj-4];
        float m1 = e1*F1, m2 = e2*F2;
        float pp = (m1 >= 1.0f) ? m1 : m2;    // = exp(lrelu(src+dst)), exact-cond by monotonicity
        p[jj] = ((bs >> jj) & 1u) ? pp : 0.0f;
    }
    union { unsigned int u[4]; s16x8 s; } pk;
#pragma unroll
    for (int z = 0; z < 4; z++)
        pk.u[z] = __builtin_amdgcn_perm(__float_as_uint(p[2*z+1]), __float_as_uint(p[2*z]), 0x07060302u);
    return pk.s;
}

__global__ __launch_bounds__(256, 4) void k_attn(const unsigned short* __restrict__ hTt,
        const unsigned int* __restrict__ bits, const float* __restrict__ E1a,
        const float* __restrict__ E2a, const float* __restrict__ F1a,
        const float* __restrict__ F2a, float* __restrict__ out){
    __shared__ float accL[4][16][64];
    __shared__ float Sl[4][16];
    const int bh = blockIdx.x;
    const int b = bh >> 2, head = bh & 3;
    const int wave = threadIdx.x >> 6, lane = threadIdx.x & 63;
    const int q = lane >> 4, t = lane & 15, q8 = q*8;
    const int i0 = blockIdx.y*64;
    float E1[4], E2[4];
#pragma unroll
    for (int f = 0; f < 4; f++){
        E1[f] = E1a[bh*2048 + i0 + f*16 + t];
        E2[f] = E2a[bh*2048 + i0 + f*16 + t];
    }
    const unsigned int* bR = bits + (i0 + t)*64 + wave*16;   // frag f: +f*1024, it: +it
    const float* F1p = F1a + bh*2048 + wave*512 + q8;
    const float* F2p = F2a + bh*2048 + wave*512 + q8;
    const unsigned short* vB = hTt + bh*131072 + wave*32768 + (q>>1)*1024 + (q&1)*8 + t*16;
    f32x4 acc[4][4];
    f32x4 sacc[4];
#pragma unroll
    for (int f = 0; f < 4; f++){
        sacc[f] = (f32x4){0.f,0.f,0.f,0.f};
#pragma unroll
        for (int d = 0; d < 4; d++) acc[f][d] = (f32x4){0.f,0.f,0.f,0.f};
    }
    s16x8 ones;
#pragma unroll
    for (int j = 0; j < 8; j++) ones[j] = (short)0x3F80;   // bf16 1.0
    for (int it = 0; it < 16; ++it){
        const unsigned short* vp = vB + it*2048;
        s16x8 h0 = *reinterpret_cast<const s16x8*>(vp);
        s16x8 h1 = *reinterpret_cast<const s16x8*>(vp + 256);
        s16x8 h2 = *reinterpret_cast<const s16x8*>(vp + 512);
        s16x8 h3 = *reinterpret_cast<const s16x8*>(vp + 768);
        f32x4 f1lo = *reinterpret_cast<const f32x4*>(F1p + it*32);
        f32x4 f1hi = *reinterpret_cast<const f32x4*>(F1p + it*32 + 4);
        f32x4 f2lo = *reinterpret_cast<const f32x4*>(F2p + it*32);
        f32x4 f2hi = *reinterpret_cast<const f32x4*>(F2p + it*32 + 4);
#pragma unroll
        for (int f = 0; f < 4; f++){
            unsigned int bs = bR[f*1024 + it] >> q8;
            s16x8 pf = make_p2(bs, E1[f], E2[f], f1lo, f1hi, f2lo, f2hi);
            acc[f][0] = __builtin_amdgcn_mfma_f32_16x16x32_bf16(pf, h0, acc[f][0], 0,0,0);
            acc[f][1] = __builtin_amdgcn_mfma_f32_16x16x32_bf16(pf, h1, acc[f][1], 0,0,0);
            acc[f][2] = __builtin_amdgcn_mfma_f32_16x16x32_bf16(pf, h2, acc[f][2], 0,0,0);
            acc[f][3] = __builtin_amdgcn_mfma_f32_16x16x32_bf16(pf, h3, acc[f][3], 0,0,0);
            sacc[f]   = __builtin_amdgcn_mfma_f32_16x16x32_bf16(pf, ones, sacc[f], 0,0,0);
        }
    }
    // ---- epilogue: R7-validated combine pattern, executed 4x ----
#pragma unroll
    for (int f = 0; f < 4; f++){
        if (f) __syncthreads();               // prior combine reads done before overwrite
#pragma unroll
        for (int reg = 0; reg < 4; reg++){
            int r = q*4 + reg;
            accL[wave][r][ 0 + t] = acc[f][0][reg];
            accL[wave][r][16 + t] = acc[f][1][reg];
            accL[wave][r][32 + t] = acc[f][2][reg];
            accL[wave][r][48 + t] = acc[f][3][reg];
        }
        if (t == 0){
#pragma unroll
            for (int reg = 0; reg < 4; reg++) Sl[wave][q*4 + reg] = sacc[f][reg];  // all cols equal
        }
        __syncthreads();
        const int tid = threadIdx.x;
        const int row = tid >> 4;
        const int d   = (tid & 15) * 4;
        f32x4 v0 = *reinterpret_cast<const f32x4*>(&accL[0][row][d]);
        f32x4 v1 = *reinterpret_cast<const f32x4*>(&accL[1][row][d]);
        f32x4 v2 = *reinterpret_cast<const f32x4*>(&accL[2][row][d]);
        f32x4 v3 = *reinterpret_cast<const f32x4*>(&accL[3][row][d]);
        float Ssum = Sl[0][row] + Sl[1][row] + Sl[2][row] + Sl[3][row];
        float rS = 1.0f / Ssum;
        f32x4 v;
#pragma unroll
        for (int c = 0; c < 4; c++){
            float vv = (v0[c] + v1[c] + v2[c] + v3[c]) * rS;
            v[c] = vv > 0.f ? vv : (__expf(vv) - 1.0f);   // ELU
        }
        *reinterpret_cast<f32x4*>(out + (b*2048 + i0 + f*16 + row)*256 + head*64 + d) = v;
    }
}

extern "C" void kernel_launch(void* const* d_in, const int* in_sizes, int n_in,
                              void* d_out, int out_size, void* d_ws, size_t ws_size,
                              hipStream_t stream) {
    const float* x     = (const float*)d_in[0];  // [4,2048,256] f32
    const int*   Amask = (const int*)d_in[1];    // [2048,2048] int32
    const float* W     = (const float*)d_in[2];  // [256,256] f32
    const float* a_src = (const float*)d_in[3];  // [4,64] f32
    const float* a_dst = (const float*)d_in[4];  // [4,64] f32
    float* out = (float*)d_out;                  // [4,2048,256] f32

    char* ws = (char*)d_ws;
    unsigned short*     hTt  = (unsigned short*)(ws);                         // 4 MB
    unsigned long long* bits = (unsigned long long*)(ws + (4u<<20));          // 512 KB
    unsigned short*     WT   = (unsigned short*)(ws + (4u<<20) + (512u<<10)); // 128 KB
    float*              E1a  = (float*)(ws + (4u<<20) + (640u<<10));          // 128 KB
    float*              E2a  = (float*)(ws + (4u<<20) + (768u<<10));          // 128 KB
    float*              F1a  = (float*)(ws + (4u<<20) + (896u<<10));          // 128 KB
    float*              F2a  = (float*)(ws + (4u<<20) + (1024u<<10));         // 128 KB

    hipLaunchKernelGGL(k_prep, dim3(2304),    dim3(256), 0, stream, W, WT, Amask, (unsigned long long*)bits);
    hipLaunchKernelGGL(k_gemm, dim3(128, 4),  dim3(256), 0, stream, x, WT, a_src, a_dst, hTt, E1a, E2a, F1a, F2a);
    hipLaunchKernelGGL(k_attn, dim3(16, 32),  dim3(256), 0, stream, hTt, (const unsigned int*)bits, E1a, E2a, F1a, F2a, out);
}

// Round 9
// 125.320 us; speedup vs baseline: 1.1842x; 1.1842x over previous
//
#include <hip/hip_runtime.h>

typedef float  f32x4 __attribute__((ext_vector_type(4)));
typedef short  s16x8 __attribute__((ext_vector_type(8)));

__device__ __forceinline__ unsigned short f2bf(float f){
    unsigned int u = __float_as_uint(f);
    u = u + 0x7FFFu + ((u >> 16) & 1u);      // RNE
    return (unsigned short)(u >> 16);
}

// ---------------- K0: merged prep — bits (blocks 0..2047) + WT (blocks 2048..2303) -------
__global__ void k_prep(const float* __restrict__ W, unsigned short* __restrict__ WT,
                       const int* __restrict__ mask, unsigned long long* __restrict__ bits64){
    int bid = blockIdx.x;
    if (bid < 2048){
        int i = bid;
        int wave = threadIdx.x >> 6, lane = threadIdx.x & 63;
        for (int c = wave; c < 32; c += 4){
            int v = mask[i*2048 + c*64 + lane];
            unsigned long long b = __ballot(v != 0);
            if (lane == 0) bits64[i*32 + c] = b;
        }
    } else {
        int c = bid - 2048, k = threadIdx.x;
        WT[c*256 + k] = f2bf(W[k*256 + c]);
    }
}

// ---------------- K1: h = x @ W, fused src/dst -> E1,E2,F1,F2 (R8-validated) ----
__global__ __launch_bounds__(256) void k_gemm(const float* __restrict__ x,
        const unsigned short* __restrict__ WT,
        const float* __restrict__ a_src, const float* __restrict__ a_dst,
        unsigned short* __restrict__ hTt, float* __restrict__ E1a, float* __restrict__ E2a,
        float* __restrict__ F1a, float* __restrict__ F2a){
    const int wave = threadIdx.x >> 6, lane = threadIdx.x & 63;
    const int q = lane >> 4, t = lane & 15;
    const int m0 = blockIdx.x*64 + wave*16;   // row tile (r = b*2048+n)
    const int head = blockIdx.y;
    f32x4 acc[4] = {{0,0,0,0},{0,0,0,0},{0,0,0,0},{0,0,0,0}};
    const int row = m0 + t;
    for (int k = 0; k < 256; k += 32){
        int kk = k + q*8;
        const float* xp = x + row*256 + kk;
        f32x4 x0 = *reinterpret_cast<const f32x4*>(xp);
        f32x4 x1 = *reinterpret_cast<const f32x4*>(xp + 4);
        s16x8 a;
#pragma unroll
        for (int j = 0; j < 4; j++){ a[j] = (short)f2bf(x0[j]); a[j+4] = (short)f2bf(x1[j]); }
#pragma unroll
        for (int dblk = 0; dblk < 4; dblk++){
            s16x8 bfr = *reinterpret_cast<const s16x8*>(WT + (head*64 + dblk*16 + t)*256 + kk);
            acc[dblk] = __builtin_amdgcn_mfma_f32_16x16x32_bf16(a, bfr, acc[dblk], 0, 0, 0);
        }
    }
    const int b = m0 >> 11;                   // tile never straddles batch boundary
    const int bh = b*4 + head;
    const int jb = (m0 & 2047) >> 4;
    float as_[4], ad_[4];
#pragma unroll
    for (int dblk = 0; dblk < 4; dblk++){
        as_[dblk] = a_src[head*64 + dblk*16 + t];
        ad_[dblk] = a_dst[head*64 + dblk*16 + t];
    }
#pragma unroll
    for (int reg = 0; reg < 4; reg++){
        float sv = acc[0][reg]*as_[0] + acc[1][reg]*as_[1] + acc[2][reg]*as_[2] + acc[3][reg]*as_[3];
        float dv = acc[0][reg]*ad_[0] + acc[1][reg]*ad_[1] + acc[2][reg]*ad_[2] + acc[3][reg]*ad_[3];
#pragma unroll
        for (int off = 1; off < 16; off <<= 1){
            sv += __shfl_xor(sv, off);
            dv += __shfl_xor(dv, off);
        }
        if (t == 0){
            int n = (m0 & 2047) + q*4 + reg;
            E1a[bh*2048 + n] = __expf(sv);
            E2a[bh*2048 + n] = __expf(0.2f*sv);
            F1a[bh*2048 + n] = __expf(dv);
            F2a[bh*2048 + n] = __expf(0.2f*dv);
        }
    }
#pragma unroll
    for (int dblk = 0; dblk < 4; dblk++){
        int d = dblk*16 + t;
#pragma unroll
        for (int reg = 0; reg < 4; reg++){
            int jj = q*4 + reg;               // n = m0 + jj
            hTt[((bh*128 + jb)*64 + d)*16 + jj] = f2bf(acc[dblk][reg]);
        }
    }
}

// ---------------- K2: fused masked softmax + PV + ELU ----------------
// R7-validated 2-fragment structure (resource-safe), R8-validated factorized exp.
// grid (16 bh, 64 i-tiles of 32 rows), block 256 = 4 waves, wave = 512-wide j-chunk.
__device__ __forceinline__ s16x8 make_p2(unsigned int bs, float e1, float e2,
        f32x4 f1lo, f32x4 f1hi, f32x4 f2lo, f32x4 f2hi){
    float p[8];
#pragma unroll
    for (int jj = 0; jj < 8; jj++){
        float F1 = (jj < 4) ? f1lo[jj] : f1hi[jj-4];
        float F2 = (jj < 4) ? f2lo[jj] : f2hi[jj-4];
        float m1 = e1*F1, m2 = e2*F2;
        float pp = (m1 >= 1.0f) ? m1 : m2;    // = exp(lrelu(src+dst)), exact-cond by monotonicity
        p[jj] = ((bs >> jj) & 1u) ? pp : 0.0f;
    }
    union { unsigned int u[4]; s16x8 s; } pk;
#pragma unroll
    for (int z = 0; z < 4; z++)
        pk.u[z] = __builtin_amdgcn_perm(__float_as_uint(p[2*z+1]), __float_as_uint(p[2*z]), 0x07060302u);
    return pk.s;
}

__global__ __launch_bounds__(256, 4) void k_attn(const unsigned short* __restrict__ hTt,
        const unsigned int* __restrict__ bits, const float* __restrict__ E1a,
        const float* __restrict__ E2a, const float* __restrict__ F1a,
        const float* __restrict__ F2a, float* __restrict__ out){
    __shared__ float accL[4][16][64];
    __shared__ float Sl[4][16];
    const int bh = blockIdx.x;
    const int b = bh >> 2, head = bh & 3;
    const int wave = threadIdx.x >> 6, lane = threadIdx.x & 63;
    const int q = lane >> 4, t = lane & 15, q8 = q*8;
    const int i0 = blockIdx.y*32;
    const float E10 = E1a[bh*2048 + i0 + t];
    const float E20 = E2a[bh*2048 + i0 + t];
    const float E11 = E1a[bh*2048 + i0 + 16 + t];
    const float E21 = E2a[bh*2048 + i0 + 16 + t];
    const unsigned int* bR0 = bits + (i0 + t)*64 + wave*16;   // u32 word covers 32 j-cols
    const unsigned int* bR1 = bR0 + 16*64;
    const float* F1p = F1a + bh*2048 + wave*512 + q8;
    const float* F2p = F2a + bh*2048 + wave*512 + q8;
    const unsigned short* vB = hTt + bh*131072 + wave*32768 + (q>>1)*1024 + (q&1)*8 + t*16;
    f32x4 a00={0,0,0,0},a01={0,0,0,0},a02={0,0,0,0},a03={0,0,0,0};
    f32x4 a10={0,0,0,0},a11={0,0,0,0},a12={0,0,0,0},a13={0,0,0,0};
    f32x4 s0acc={0,0,0,0}, s1acc={0,0,0,0};
    s16x8 ones;
#pragma unroll
    for (int j = 0; j < 8; j++) ones[j] = (short)0x3F80;   // bf16 1.0
    for (int it = 0; it < 16; ++it){
        const unsigned short* vp = vB + it*2048;
        s16x8 h0 = *reinterpret_cast<const s16x8*>(vp);
        s16x8 h1 = *reinterpret_cast<const s16x8*>(vp + 256);
        s16x8 h2 = *reinterpret_cast<const s16x8*>(vp + 512);
        s16x8 h3 = *reinterpret_cast<const s16x8*>(vp + 768);
        f32x4 f1lo = *reinterpret_cast<const f32x4*>(F1p + it*32);
        f32x4 f1hi = *reinterpret_cast<const f32x4*>(F1p + it*32 + 4);
        f32x4 f2lo = *reinterpret_cast<const f32x4*>(F2p + it*32);
        f32x4 f2hi = *reinterpret_cast<const f32x4*>(F2p + it*32 + 4);
        unsigned int bs0 = bR0[it] >> q8;
        unsigned int bs1 = bR1[it] >> q8;
        s16x8 p0 = make_p2(bs0, E10, E20, f1lo, f1hi, f2lo, f2hi);
        s16x8 p1 = make_p2(bs1, E11, E21, f1lo, f1hi, f2lo, f2hi);
        a00 = __builtin_amdgcn_mfma_f32_16x16x32_bf16(p0, h0, a00, 0,0,0);
        a01 = __builtin_amdgcn_mfma_f32_16x16x32_bf16(p0, h1, a01, 0,0,0);
        a02 = __builtin_amdgcn_mfma_f32_16x16x32_bf16(p0, h2, a02, 0,0,0);
        a03 = __builtin_amdgcn_mfma_f32_16x16x32_bf16(p0, h3, a03, 0,0,0);
        s0acc = __builtin_amdgcn_mfma_f32_16x16x32_bf16(p0, ones, s0acc, 0,0,0);
        a10 = __builtin_amdgcn_mfma_f32_16x16x32_bf16(p1, h0, a10, 0,0,0);
        a11 = __builtin_amdgcn_mfma_f32_16x16x32_bf16(p1, h1, a11, 0,0,0);
        a12 = __builtin_amdgcn_mfma_f32_16x16x32_bf16(p1, h2, a12, 0,0,0);
        a13 = __builtin_amdgcn_mfma_f32_16x16x32_bf16(p1, h3, a13, 0,0,0);
        s1acc = __builtin_amdgcn_mfma_f32_16x16x32_bf16(p1, ones, s1acc, 0,0,0);
    }
    // ---- epilogue: R7-validated combine, executed twice ----
#pragma unroll
    for (int half = 0; half < 2; half++){
        f32x4 c0 = half ? a10 : a00;
        f32x4 c1 = half ? a11 : a01;
        f32x4 c2 = half ? a12 : a02;
        f32x4 c3 = half ? a13 : a03;
        f32x4 sc = half ? s1acc : s0acc;
        if (half) __syncthreads();            // previous combine reads done before overwrite
#pragma unroll
        for (int reg = 0; reg < 4; reg++){
            int r = q*4 + reg;
            accL[wave][r][ 0 + t] = c0[reg];
            accL[wave][r][16 + t] = c1[reg];
            accL[wave][r][32 + t] = c2[reg];
            accL[wave][r][48 + t] = c3[reg];
        }
        if (t == 0){
#pragma unroll
            for (int reg = 0; reg < 4; reg++) Sl[wave][q*4 + reg] = sc[reg];  // all cols equal
        }
        __syncthreads();
        const int tid = threadIdx.x;
        const int row = tid >> 4;
        const int d   = (tid & 15) * 4;
        f32x4 v0 = *reinterpret_cast<const f32x4*>(&accL[0][row][d]);
        f32x4 v1 = *reinterpret_cast<const f32x4*>(&accL[1][row][d]);
        f32x4 v2 = *reinterpret_cast<const f32x4*>(&accL[2][row][d]);
        f32x4 v3 = *reinterpret_cast<const f32x4*>(&accL[3][row][d]);
        float Ssum = Sl[0][row] + Sl[1][row] + Sl[2][row] + Sl[3][row];
        float rS = 1.0f / Ssum;
        f32x4 v;
#pragma unroll
        for (int c = 0; c < 4; c++){
            float vv = (v0[c] + v1[c] + v2[c] + v3[c]) * rS;
            v[c] = vv > 0.f ? vv : (__expf(vv) - 1.0f);   // ELU
        }
        *reinterpret_cast<f32x4*>(out + (b*2048 + i0 + half*16 + row)*256 + head*64 + d) = v;
    }
}

extern "C" void kernel_launch(void* const* d_in, const int* in_sizes, int n_in,
                              void* d_out, int out_size, void* d_ws, size_t ws_size,
                              hipStream_t stream) {
    const float* x     = (const float*)d_in[0];  // [4,2048,256] f32
    const int*   Amask = (const int*)d_in[1];    // [2048,2048] int32
    const float* W     = (const float*)d_in[2];  // [256,256] f32
    const float* a_src = (const float*)d_in[3];  // [4,64] f32
    const float* a_dst = (const float*)d_in[4];  // [4,64] f32
    float* out = (float*)d_out;                  // [4,2048,256] f32

    char* ws = (char*)d_ws;
    unsigned short*     hTt  = (unsigned short*)(ws);                         // 4 MB
    unsigned long long* bits = (unsigned long long*)(ws + (4u<<20));          // 512 KB
    unsigned short*     WT   = (unsigned short*)(ws + (4u<<20) + (512u<<10)); // 128 KB
    float*              E1a  = (float*)(ws + (4u<<20) + (640u<<10));          // 128 KB
    float*              E2a  = (float*)(ws + (4u<<20) + (768u<<10));          // 128 KB
    float*              F1a  = (float*)(ws + (4u<<20) + (896u<<10));          // 128 KB
    float*              F2a  = (float*)(ws + (4u<<20) + (1024u<<10));         // 128 KB

    hipLaunchKernelGGL(k_prep, dim3(2304),    dim3(256), 0, stream, W, WT, Amask, (unsigned long long*)bits);
    hipLaunchKernelGGL(k_gemm, dim3(128, 4),  dim3(256), 0, stream, x, WT, a_src, a_dst, hTt, E1a, E2a, F1a, F2a);
    hipLaunchKernelGGL(k_attn, dim3(16, 64),  dim3(256), 0, stream, hTt, (const unsigned int*)bits, E1a, E2a, F1a, F2a, out);
}

// Round 10
// 112.835 us; speedup vs baseline: 1.3152x; 1.1107x over previous
//
#include <hip/hip_runtime.h>

typedef float  f32x4 __attribute__((ext_vector_type(4)));
typedef short  s16x8 __attribute__((ext_vector_type(8)));

__device__ __forceinline__ unsigned short f2bf(float f){
    unsigned int u = __float_as_uint(f);
    u = u + 0x7FFFu + ((u >> 16) & 1u);      // RNE
    return (unsigned short)(u >> 16);
}

// ---------------- K0: merged prep — bitsT (blocks 0..2047) + WT (blocks 2048..2303) ------
// bitsT layout: [jw=j/32][i]  (u32 word covers j-cols [jw*32, jw*32+32) of row i)
__global__ void k_prep(const float* __restrict__ W, unsigned short* __restrict__ WT,
                       const int* __restrict__ mask, unsigned int* __restrict__ bitsT){
    int bid = blockIdx.x;
    if (bid < 2048){
        int i = bid;
        int wave = threadIdx.x >> 6, lane = threadIdx.x & 63;
        for (int c = wave; c < 32; c += 4){
            int v = mask[i*2048 + c*64 + lane];
            unsigned long long b = __ballot(v != 0);
            if (lane == 0){
                bitsT[(2*c    )*2048 + i] = (unsigned int)(b & 0xFFFFFFFFu);
                bitsT[(2*c + 1)*2048 + i] = (unsigned int)(b >> 32);
            }
        }
    } else {
        int c = bid - 2048, k = threadIdx.x;
        WT[c*256 + k] = f2bf(W[k*256 + c]);
    }
}

// ---------------- K1: h = x @ W, fused src/dst -> E1,E2,F1,F2 (R8/R9-validated) ----
__global__ __launch_bounds__(256) void k_gemm(const float* __restrict__ x,
        const unsigned short* __restrict__ WT,
        const float* __restrict__ a_src, const float* __restrict__ a_dst,
        unsigned short* __restrict__ hTt, float* __restrict__ E1a, float* __restrict__ E2a,
        float* __restrict__ F1a, float* __restrict__ F2a){
    const int wave = threadIdx.x >> 6, lane = threadIdx.x & 63;
    const int q = lane >> 4, t = lane & 15;
    const int m0 = blockIdx.x*64 + wave*16;   // row tile (r = b*2048+n)
    const int head = blockIdx.y;
    f32x4 acc[4] = {{0,0,0,0},{0,0,0,0},{0,0,0,0},{0,0,0,0}};
    const int row = m0 + t;
    for (int k = 0; k < 256; k += 32){
        int kk = k + q*8;
        const float* xp = x + row*256 + kk;
        f32x4 x0 = *reinterpret_cast<const f32x4*>(xp);
        f32x4 x1 = *reinterpret_cast<const f32x4*>(xp + 4);
        s16x8 a;
#pragma unroll
        for (int j = 0; j < 4; j++){ a[j] = (short)f2bf(x0[j]); a[j+4] = (short)f2bf(x1[j]); }
#pragma unroll
        for (int dblk = 0; dblk < 4; dblk++){
            s16x8 bfr = *reinterpret_cast<const s16x8*>(WT + (head*64 + dblk*16 + t)*256 + kk);
            acc[dblk] = __builtin_amdgcn_mfma_f32_16x16x32_bf16(a, bfr, acc[dblk], 0, 0, 0);
        }
    }
    const int b = m0 >> 11;                   // tile never straddles batch boundary
    const int bh = b*4 + head;
    const int jb = (m0 & 2047) >> 4;
    float as_[4], ad_[4];
#pragma unroll
    for (int dblk = 0; dblk < 4; dblk++){
        as_[dblk] = a_src[head*64 + dblk*16 + t];
        ad_[dblk] = a_dst[head*64 + dblk*16 + t];
    }
#pragma unroll
    for (int reg = 0; reg < 4; reg++){
        float sv = acc[0][reg]*as_[0] + acc[1][reg]*as_[1] + acc[2][reg]*as_[2] + acc[3][reg]*as_[3];
        float dv = acc[0][reg]*ad_[0] + acc[1][reg]*ad_[1] + acc[2][reg]*ad_[2] + acc[3][reg]*ad_[3];
#pragma unroll
        for (int off = 1; off < 16; off <<= 1){
            sv += __shfl_xor(sv, off);
            dv += __shfl_xor(dv, off);
        }
        if (t == 0){
            int n = (m0 & 2047) + q*4 + reg;
            E1a[bh*2048 + n] = __expf(sv);
            E2a[bh*2048 + n] = __expf(0.2f*sv);
            F1a[bh*2048 + n] = __expf(dv);
            F2a[bh*2048 + n] = __expf(0.2f*dv);
        }
    }
#pragma unroll
    for (int dblk = 0; dblk < 4; dblk++){
        int d = dblk*16 + t;
#pragma unroll
        for (int reg = 0; reg < 4; reg++){
            int jj = q*4 + reg;               // n = m0 + jj
            hTt[((bh*128 + jb)*64 + d)*16 + jj] = f2bf(acc[dblk][reg]);
        }
    }
}

// ---------------- K2: fused masked softmax + PV + ELU ----------------
// R9-validated structure; only the bits read is re-indexed (transposed, coalesced).
__device__ __forceinline__ s16x8 make_p2(unsigned int bs, float e1, float e2,
        f32x4 f1lo, f32x4 f1hi, f32x4 f2lo, f32x4 f2hi){
    float p[8];
#pragma unroll
    for (int jj = 0; jj < 8; jj++){
        float F1 = (jj < 4) ? f1lo[jj] : f1hi[jj-4];
        float F2 = (jj < 4) ? f2lo[jj] : f2hi[jj-4];
        float m1 = e1*F1, m2 = e2*F2;
        float pp = (m1 >= 1.0f) ? m1 : m2;    // = exp(lrelu(src+dst)), exact-cond by monotonicity
        p[jj] = ((bs >> jj) & 1u) ? pp : 0.0f;
    }
    union { unsigned int u[4]; s16x8 s; } pk;
#pragma unroll
    for (int z = 0; z < 4; z++)
        pk.u[z] = __builtin_amdgcn_perm(__float_as_uint(p[2*z+1]), __float_as_uint(p[2*z]), 0x07060302u);
    return pk.s;
}

__global__ __launch_bounds__(256, 4) void k_attn(const unsigned short* __restrict__ hTt,
        const unsigned int* __restrict__ bitsT, const float* __restrict__ E1a,
        const float* __restrict__ E2a, const float* __restrict__ F1a,
        const float* __restrict__ F2a, float* __restrict__ out){
    __shared__ float accL[4][16][64];
    __shared__ float Sl[4][16];
    const int bh = blockIdx.x;
    const int b = bh >> 2, head = bh & 3;
    const int wave = threadIdx.x >> 6, lane = threadIdx.x & 63;
    const int q = lane >> 4, t = lane & 15, q8 = q*8;
    const int i0 = blockIdx.y*32;
    const float E10 = E1a[bh*2048 + i0 + t];
    const float E20 = E2a[bh*2048 + i0 + t];
    const float E11 = E1a[bh*2048 + i0 + 16 + t];
    const float E21 = E2a[bh*2048 + i0 + 16 + t];
    // transposed bits: word jw = wave*16 + it covers j-cols [jw*32, jw*32+32)
    const unsigned int* bT = bitsT + (wave*16)*2048 + i0 + t;
    const float* F1p = F1a + bh*2048 + wave*512 + q8;
    const float* F2p = F2a + bh*2048 + wave*512 + q8;
    const unsigned short* vB = hTt + bh*131072 + wave*32768 + (q>>1)*1024 + (q&1)*8 + t*16;
    f32x4 a00={0,0,0,0},a01={0,0,0,0},a02={0,0,0,0},a03={0,0,0,0};
    f32x4 a10={0,0,0,0},a11={0,0,0,0},a12={0,0,0,0},a13={0,0,0,0};
    f32x4 s0acc={0,0,0,0}, s1acc={0,0,0,0};
    s16x8 ones;
#pragma unroll
    for (int j = 0; j < 8; j++) ones[j] = (short)0x3F80;   // bf16 1.0
    for (int it = 0; it < 16; ++it){
        const unsigned short* vp = vB + it*2048;
        s16x8 h0 = *reinterpret_cast<const s16x8*>(vp);
        s16x8 h1 = *reinterpret_cast<const s16x8*>(vp + 256);
        s16x8 h2 = *reinterpret_cast<const s16x8*>(vp + 512);
        s16x8 h3 = *reinterpret_cast<const s16x8*>(vp + 768);
        f32x4 f1lo = *reinterpret_cast<const f32x4*>(F1p + it*32);
        f32x4 f1hi = *reinterpret_cast<const f32x4*>(F1p + it*32 + 4);
        f32x4 f2lo = *reinterpret_cast<const f32x4*>(F2p + it*32);
        f32x4 f2hi = *reinterpret_cast<const f32x4*>(F2p + it*32 + 4);
        unsigned int bs0 = bT[it*2048]      >> q8;
        unsigned int bs1 = bT[it*2048 + 16] >> q8;
        s16x8 p0 = make_p2(bs0, E10, E20, f1lo, f1hi, f2lo, f2hi);
        s16x8 p1 = make_p2(bs1, E11, E21, f1lo, f1hi, f2lo, f2hi);
        a00 = __builtin_amdgcn_mfma_f32_16x16x32_bf16(p0, h0, a00, 0,0,0);
        a01 = __builtin_amdgcn_mfma_f32_16x16x32_bf16(p0, h1, a01, 0,0,0);
        a02 = __builtin_amdgcn_mfma_f32_16x16x32_bf16(p0, h2, a02, 0,0,0);
        a03 = __builtin_amdgcn_mfma_f32_16x16x32_bf16(p0, h3, a03, 0,0,0);
        s0acc = __builtin_amdgcn_mfma_f32_16x16x32_bf16(p0, ones, s0acc, 0,0,0);
        a10 = __builtin_amdgcn_mfma_f32_16x16x32_bf16(p1, h0, a10, 0,0,0);
        a11 = __builtin_amdgcn_mfma_f32_16x16x32_bf16(p1, h1, a11, 0,0,0);
        a12 = __builtin_amdgcn_mfma_f32_16x16x32_bf16(p1, h2, a12, 0,0,0);
        a13 = __builtin_amdgcn_mfma_f32_16x16x32_bf16(p1, h3, a13, 0,0,0);
        s1acc = __builtin_amdgcn_mfma_f32_16x16x32_bf16(p1, ones, s1acc, 0,0,0);
    }
    // ---- epilogue: R7-validated combine, executed twice ----
#pragma unroll
    for (int half = 0; half < 2; half++){
        f32x4 c0 = half ? a10 : a00;
        f32x4 c1 = half ? a11 : a01;
        f32x4 c2 = half ? a12 : a02;
        f32x4 c3 = half ? a13 : a03;
        f32x4 sc = half ? s1acc : s0acc;
        if (half) __syncthreads();            // previous combine reads done before overwrite
#pragma unroll
        for (int reg = 0; reg < 4; reg++){
            int r = q*4 + reg;
            accL[wave][r][ 0 + t] = c0[reg];
            accL[wave][r][16 + t] = c1[reg];
            accL[wave][r][32 + t] = c2[reg];
            accL[wave][r][48 + t] = c3[reg];
        }
        if (t == 0){
#pragma unroll
            for (int reg = 0; reg < 4; reg++) Sl[wave][q*4 + reg] = sc[reg];  // all cols equal
        }
        __syncthreads();
        const int tid = threadIdx.x;
        const int row = tid >> 4;
        const int d   = (tid & 15) * 4;
        f32x4 v0 = *reinterpret_cast<const f32x4*>(&accL[0][row][d]);
        f32x4 v1 = *reinterpret_cast<const f32x4*>(&accL[1][row][d]);
        f32x4 v2 = *reinterpret_cast<const f32x4*>(&accL[2][row][d]);
        f32x4 v3 = *reinterpret_cast<const f32x4*>(&accL[3][row][d]);
        float Ssum = Sl[0][row] + Sl[1][row] + Sl[2][row] + Sl[3][row];
        float rS = 1.0f / Ssum;
        f32x4 v;
#pragma unroll
        for (int c = 0; c < 4; c++){
            float vv = (v0[c] + v1[c] + v2[c] + v3[c]) * rS;
            v[c] = vv > 0.f ? vv : (__expf(vv) - 1.0f);   // ELU
        }
        *reinterpret_cast<f32x4*>(out + (b*2048 + i0 + half*16 + row)*256 + head*64 + d) = v;
    }
}

extern "C" void kernel_launch(void* const* d_in, const int* in_sizes, int n_in,
                              void* d_out, int out_size, void* d_ws, size_t ws_size,
                              hipStream_t stream) {
    const float* x     = (const float*)d_in[0];  // [4,2048,256] f32
    const int*   Amask = (const int*)d_in[1];    // [2048,2048] int32
    const float* W     = (const float*)d_in[2];  // [256,256] f32
    const float* a_src = (const float*)d_in[3];  // [4,64] f32
    const float* a_dst = (const float*)d_in[4];  // [4,64] f32
    float* out = (float*)d_out;                  // [4,2048,256] f32

    char* ws = (char*)d_ws;
    unsigned short* hTt   = (unsigned short*)(ws);                         // 4 MB
    unsigned int*   bitsT = (unsigned int*)(ws + (4u<<20));                // 512 KB
    unsigned short* WT    = (unsigned short*)(ws + (4u<<20) + (512u<<10)); // 128 KB
    float*          E1a   = (float*)(ws + (4u<<20) + (640u<<10));          // 128 KB
    float*          E2a   = (float*)(ws + (4u<<20) + (768u<<10));          // 128 KB
    float*          F1a   = (float*)(ws + (4u<<20) + (896u<<10));          // 128 KB
    float*          F2a   = (float*)(ws + (4u<<20) + (1024u<<10));         // 128 KB

    hipLaunchKernelGGL(k_prep, dim3(2304),    dim3(256), 0, stream, W, WT, Amask, bitsT);
    hipLaunchKernelGGL(k_gemm, dim3(128, 4),  dim3(256), 0, stream, x, WT, a_src, a_dst, hTt, E1a, E2a, F1a, F2a);
    hipLaunchKernelGGL(k_attn, dim3(16, 64),  dim3(256), 0, stream, hTt, bitsT, E1a, E2a, F1a, F2a, out);
}

// Round 11
// 112.066 us; speedup vs baseline: 1.3243x; 1.0069x over previous
//
#include <hip/hip_runtime.h>

typedef float  f32x4 __attribute__((ext_vector_type(4)));
typedef short  s16x8 __attribute__((ext_vector_type(8)));

__device__ __forceinline__ unsigned short f2bf(float f){
    unsigned int u = __float_as_uint(f);
    u = u + 0x7FFFu + ((u >> 16) & 1u);      // RNE
    return (unsigned short)(u >> 16);
}

// ---------------- K0: merged prep — bitsT (blocks 0..2047) + WTf (blocks 2048..2303) -----
// bitsT: [jw=j/32][i].  WTf fragment-major: idx = ((dgT*8 + kT)*16 + t)*32 + kj
//   where dg = dgT*16+t (output col), k = kT*32+kj. Element = W[k][dg] (bf16).
__global__ void k_prep(const float* __restrict__ W, unsigned short* __restrict__ WTf,
                       const int* __restrict__ mask, unsigned int* __restrict__ bitsT){
    int bid = blockIdx.x;
    if (bid < 2048){
        int i = bid;
        int wave = threadIdx.x >> 6, lane = threadIdx.x & 63;
        for (int c = wave; c < 32; c += 4){
            int v = mask[i*2048 + c*64 + lane];
            unsigned long long b = __ballot(v != 0);
            if (lane == 0){
                bitsT[(2*c    )*2048 + i] = (unsigned int)(b & 0xFFFFFFFFu);
                bitsT[(2*c + 1)*2048 + i] = (unsigned int)(b >> 32);
            }
        }
    } else {
        int dg = bid - 2048, k = threadIdx.x;
        int dgT = dg >> 4, tt = dg & 15, kT = k >> 5, kj = k & 31;
        WTf[((dgT*8 + kT)*16 + tt)*32 + kj] = f2bf(W[k*256 + dg]);
    }
}

// ---------------- K1: h = x @ W, fused src/dst -> E1,E2,F1,F2 ----
// R10 structure; WT fragment load re-tiled to lane-contiguous (1-segment b128).
__global__ __launch_bounds__(256) void k_gemm(const float* __restrict__ x,
        const unsigned short* __restrict__ WTf,
        const float* __restrict__ a_src, const float* __restrict__ a_dst,
        unsigned short* __restrict__ hTt, float* __restrict__ E1a, float* __restrict__ E2a,
        float* __restrict__ F1a, float* __restrict__ F2a){
    const int wave = threadIdx.x >> 6, lane = threadIdx.x & 63;
    const int q = lane >> 4, t = lane & 15;
    const int m0 = blockIdx.x*64 + wave*16;   // row tile (r = b*2048+n)
    const int head = blockIdx.y;
    f32x4 acc[4] = {{0,0,0,0},{0,0,0,0},{0,0,0,0},{0,0,0,0}};
    const int row = m0 + t;
    for (int k = 0; k < 256; k += 32){
        int kk = k + q*8;
        const float* xp = x + row*256 + kk;
        f32x4 x0 = *reinterpret_cast<const f32x4*>(xp);
        f32x4 x1 = *reinterpret_cast<const f32x4*>(xp + 4);
        s16x8 a;
#pragma unroll
        for (int j = 0; j < 4; j++){ a[j] = (short)f2bf(x0[j]); a[j+4] = (short)f2bf(x1[j]); }
#pragma unroll
        for (int dblk = 0; dblk < 4; dblk++){
            // WTf: ((dgT*8 + kT)*16 + t)*32 + q8, dgT = head*4+dblk, kT = k>>5
            s16x8 bfr = *reinterpret_cast<const s16x8*>(
                WTf + (((head*4 + dblk)*8 + (k >> 5))*16 + t)*32 + q*8);
            acc[dblk] = __builtin_amdgcn_mfma_f32_16x16x32_bf16(a, bfr, acc[dblk], 0, 0, 0);
        }
    }
    const int b = m0 >> 11;                   // tile never straddles batch boundary
    const int bh = b*4 + head;
    const int jb = (m0 & 2047) >> 4;
    float as_[4], ad_[4];
#pragma unroll
    for (int dblk = 0; dblk < 4; dblk++){
        as_[dblk] = a_src[head*64 + dblk*16 + t];
        ad_[dblk] = a_dst[head*64 + dblk*16 + t];
    }
#pragma unroll
    for (int reg = 0; reg < 4; reg++){
        float sv = acc[0][reg]*as_[0] + acc[1][reg]*as_[1] + acc[2][reg]*as_[2] + acc[3][reg]*as_[3];
        float dv = acc[0][reg]*ad_[0] + acc[1][reg]*ad_[1] + acc[2][reg]*ad_[2] + acc[3][reg]*ad_[3];
#pragma unroll
        for (int off = 1; off < 16; off <<= 1){
            sv += __shfl_xor(sv, off);
            dv += __shfl_xor(dv, off);
        }
        if (t == 0){
            int n = (m0 & 2047) + q*4 + reg;
            E1a[bh*2048 + n] = __expf(sv);
            E2a[bh*2048 + n] = __expf(0.2f*sv);
            F1a[bh*2048 + n] = __expf(dv);
            F2a[bh*2048 + n] = __expf(0.2f*dv);
        }
    }
#pragma unroll
    for (int dblk = 0; dblk < 4; dblk++){
        int d = dblk*16 + t;
#pragma unroll
        for (int reg = 0; reg < 4; reg++){
            int jj = q*4 + reg;               // n = m0 + jj
            hTt[((bh*128 + jb)*64 + d)*16 + jj] = f2bf(acc[dblk][reg]);
        }
    }
}

// ---------------- K2: fused masked softmax + PV + ELU ----------------
// R10 numerics; 4 A-fragments (64 i-rows/block) held in NAMED scalars (no arrays),
// grid (16 bh, 32 i-tiles), block 256 = 4 waves, wave = 512-wide j-chunk.
__device__ __forceinline__ s16x8 make_p2(unsigned int bs, float e1, float e2,
        f32x4 f1lo, f32x4 f1hi, f32x4 f2lo, f32x4 f2hi){
    float p[8];
#pragma unroll
    for (int jj = 0; jj < 8; jj++){
        float F1 = (jj < 4) ? f1lo[jj] : f1hi[jj-4];
        float F2 = (jj < 4) ? f2lo[jj] : f2hi[jj-4];
        float m1 = e1*F1, m2 = e2*F2;
        float pp = (m1 >= 1.0f) ? m1 : m2;    // = exp(lrelu(src+dst)), exact-cond by monotonicity
        p[jj] = ((bs >> jj) & 1u) ? pp : 0.0f;
    }
    union { unsigned int u[4]; s16x8 s; } pk;
#pragma unroll
    for (int z = 0; z < 4; z++)
        pk.u[z] = __builtin_amdgcn_perm(__float_as_uint(p[2*z+1]), __float_as_uint(p[2*z]), 0x07060302u);
    return pk.s;
}

__global__ __launch_bounds__(256, 3) void k_attn(const unsigned short* __restrict__ hTt,
        const unsigned int* __restrict__ bitsT, const float* __restrict__ E1a,
        const float* __restrict__ E2a, const float* __restrict__ F1a,
        const float* __restrict__ F2a, float* __restrict__ out){
    __shared__ float accL[4][16][64];
    __shared__ float Sl[4][16];
    const int bh = blockIdx.x;
    const int b = bh >> 2, head = bh & 3;
    const int wave = threadIdx.x >> 6, lane = threadIdx.x & 63;
    const int q = lane >> 4, t = lane & 15, q8 = q*8;
    const int i0 = blockIdx.y*64;
    const float E10 = E1a[bh*2048 + i0 +  0 + t], E20 = E2a[bh*2048 + i0 +  0 + t];
    const float E11 = E1a[bh*2048 + i0 + 16 + t], E21 = E2a[bh*2048 + i0 + 16 + t];
    const float E12 = E1a[bh*2048 + i0 + 32 + t], E22 = E2a[bh*2048 + i0 + 32 + t];
    const float E13 = E1a[bh*2048 + i0 + 48 + t], E23 = E2a[bh*2048 + i0 + 48 + t];
    const unsigned int* bT = bitsT + (wave*16)*2048 + i0 + t;   // +f*16 per fragment
    const float* F1p = F1a + bh*2048 + wave*512 + q8;
    const float* F2p = F2a + bh*2048 + wave*512 + q8;
    const unsigned short* vB = hTt + bh*131072 + wave*32768 + (q>>1)*1024 + (q&1)*8 + t*16;
    f32x4 a00={0,0,0,0},a01={0,0,0,0},a02={0,0,0,0},a03={0,0,0,0},s0acc={0,0,0,0};
    f32x4 a10={0,0,0,0},a11={0,0,0,0},a12={0,0,0,0},a13={0,0,0,0},s1acc={0,0,0,0};
    f32x4 a20={0,0,0,0},a21={0,0,0,0},a22={0,0,0,0},a23={0,0,0,0},s2acc={0,0,0,0};
    f32x4 a30={0,0,0,0},a31={0,0,0,0},a32={0,0,0,0},a33={0,0,0,0},s3acc={0,0,0,0};
    s16x8 ones;
#pragma unroll
    for (int j = 0; j < 8; j++) ones[j] = (short)0x3F80;   // bf16 1.0
    for (int it = 0; it < 16; ++it){
        const unsigned short* vp = vB + it*2048;
        s16x8 h0 = *reinterpret_cast<const s16x8*>(vp);
        s16x8 h1 = *reinterpret_cast<const s16x8*>(vp + 256);
        s16x8 h2 = *reinterpret_cast<const s16x8*>(vp + 512);
        s16x8 h3 = *reinterpret_cast<const s16x8*>(vp + 768);
        f32x4 f1lo = *reinterpret_cast<const f32x4*>(F1p + it*32);
        f32x4 f1hi = *reinterpret_cast<const f32x4*>(F1p + it*32 + 4);
        f32x4 f2lo = *reinterpret_cast<const f32x4*>(F2p + it*32);
        f32x4 f2hi = *reinterpret_cast<const f32x4*>(F2p + it*32 + 4);
        unsigned int bs0 = bT[it*2048 +  0] >> q8;
        unsigned int bs1 = bT[it*2048 + 16] >> q8;
        unsigned int bs2 = bT[it*2048 + 32] >> q8;
        unsigned int bs3 = bT[it*2048 + 48] >> q8;
        s16x8 p0 = make_p2(bs0, E10, E20, f1lo, f1hi, f2lo, f2hi);
        a00 = __builtin_amdgcn_mfma_f32_16x16x32_bf16(p0, h0, a00, 0,0,0);
        a01 = __builtin_amdgcn_mfma_f32_16x16x32_bf16(p0, h1, a01, 0,0,0);
        a02 = __builtin_amdgcn_mfma_f32_16x16x32_bf16(p0, h2, a02, 0,0,0);
        a03 = __builtin_amdgcn_mfma_f32_16x16x32_bf16(p0, h3, a03, 0,0,0);
        s0acc = __builtin_amdgcn_mfma_f32_16x16x32_bf16(p0, ones, s0acc, 0,0,0);
        s16x8 p1 = make_p2(bs1, E11, E21, f1lo, f1hi, f2lo, f2hi);
        a10 = __builtin_amdgcn_mfma_f32_16x16x32_bf16(p1, h0, a10, 0,0,0);
        a11 = __builtin_amdgcn_mfma_f32_16x16x32_bf16(p1, h1, a11, 0,0,0);
        a12 = __builtin_amdgcn_mfma_f32_16x16x32_bf16(p1, h2, a12, 0,0,0);
        a13 = __builtin_amdgcn_mfma_f32_16x16x32_bf16(p1, h3, a13, 0,0,0);
        s1acc = __builtin_amdgcn_mfma_f32_16x16x32_bf16(p1, ones, s1acc, 0,0,0);
        s16x8 p2 = make_p2(bs2, E12, E22, f1lo, f1hi, f2lo, f2hi);
        a20 = __builtin_amdgcn_mfma_f32_16x16x32_bf16(p2, h0, a20, 0,0,0);
        a21 = __builtin_amdgcn_mfma_f32_16x16x32_bf16(p2, h1, a21, 0,0,0);
        a22 = __builtin_amdgcn_mfma_f32_16x16x32_bf16(p2, h2, a22, 0,0,0);
        a23 = __builtin_amdgcn_mfma_f32_16x16x32_bf16(p2, h3, a23, 0,0,0);
        s2acc = __builtin_amdgcn_mfma_f32_16x16x32_bf16(p2, ones, s2acc, 0,0,0);
        s16x8 p3 = make_p2(bs3, E13, E23, f1lo, f1hi, f2lo, f2hi);
        a30 = __builtin_amdgcn_mfma_f32_16x16x32_bf16(p3, h0, a30, 0,0,0);
        a31 = __builtin_amdgcn_mfma_f32_16x16x32_bf16(p3, h1, a31, 0,0,0);
        a32 = __builtin_amdgcn_mfma_f32_16x16x32_bf16(p3, h2, a32, 0,0,0);
        a33 = __builtin_amdgcn_mfma_f32_16x16x32_bf16(p3, h3, a33, 0,0,0);
        s3acc = __builtin_amdgcn_mfma_f32_16x16x32_bf16(p3, ones, s3acc, 0,0,0);
    }
    // ---- epilogue: R7-validated combine pattern via inlined lambda, executed 4x ----
    auto epi = [&](f32x4 c0, f32x4 c1, f32x4 c2, f32x4 c3, f32x4 sc, int fi){
        if (fi) __syncthreads();              // previous combine reads done before overwrite
#pragma unroll
        for (int reg = 0; reg < 4; reg++){
            int r = q*4 + reg;
            accL[wave][r][ 0 + t] = c0[reg];
            accL[wave][r][16 + t] = c1[reg];
            accL[wave][r][32 + t] = c2[reg];
            accL[wave][r][48 + t] = c3[reg];
        }
        if (t == 0){
#pragma unroll
            for (int reg = 0; reg < 4; reg++) Sl[wave][q*4 + reg] = sc[reg];  // all cols equal
        }
        __syncthreads();
        const int tid = threadIdx.x;
        const int row = tid >> 4;
        const int d   = (tid & 15) * 4;
        f32x4 v0 = *reinterpret_cast<const f32x4*>(&accL[0][row][d]);
        f32x4 v1 = *reinterpret_cast<const f32x4*>(&accL[1][row][d]);
        f32x4 v2 = *reinterpret_cast<const f32x4*>(&accL[2][row][d]);
        f32x4 v3 = *reinterpret_cast<const f32x4*>(&accL[3][row][d]);
        float Ssum = Sl[0][row] + Sl[1][row] + Sl[2][row] + Sl[3][row];
        float rS = 1.0f / Ssum;
        f32x4 v;
#pragma unroll
        for (int c = 0; c < 4; c++){
            float vv = (v0[c] + v1[c] + v2[c] + v3[c]) * rS;
            v[c] = vv > 0.f ? vv : (__expf(vv) - 1.0f);   // ELU
        }
        *reinterpret_cast<f32x4*>(out + (b*2048 + i0 + fi*16 + row)*256 + head*64 + d) = v;
    };
    epi(a00, a01, a02, a03, s0acc, 0);
    epi(a10, a11, a12, a13, s1acc, 1);
    epi(a20, a21, a22, a23, s2acc, 2);
    epi(a30, a31, a32, a33, s3acc, 3);
}

extern "C" void kernel_launch(void* const* d_in, const int* in_sizes, int n_in,
                              void* d_out, int out_size, void* d_ws, size_t ws_size,
                              hipStream_t stream) {
    const float* x     = (const float*)d_in[0];  // [4,2048,256] f32
    const int*   Amask = (const int*)d_in[1];    // [2048,2048] int32
    const float* W     = (const float*)d_in[2];  // [256,256] f32
    const float* a_src = (const float*)d_in[3];  // [4,64] f32
    const float* a_dst = (const float*)d_in[4];  // [4,64] f32
    float* out = (float*)d_out;                  // [4,2048,256] f32

    char* ws = (char*)d_ws;
    unsigned short* hTt   = (unsigned short*)(ws);                         // 4 MB
    unsigned int*   bitsT = (unsigned int*)(ws + (4u<<20));                // 512 KB
    unsigned short* WTf   = (unsigned short*)(ws + (4u<<20) + (512u<<10)); // 128 KB
    float*          E1a   = (float*)(ws + (4u<<20) + (640u<<10));          // 128 KB
    float*          E2a   = (float*)(ws + (4u<<20) + (768u<<10));          // 128 KB
    float*          F1a   = (float*)(ws + (4u<<20) + (896u<<10));          // 128 KB
    float*          F2a   = (float*)(ws + (4u<<20) + (1024u<<10));         // 128 KB

    hipLaunchKernelGGL(k_prep, dim3(2304),    dim3(256), 0, stream, W, WTf, Amask, bitsT);
    hipLaunchKernelGGL(k_gemm, dim3(128, 4),  dim3(256), 0, stream, x, WTf, a_src, a_dst, hTt, E1a, E2a, F1a, F2a);
    hipLaunchKernelGGL(k_attn, dim3(16, 32),  dim3(256), 0, stream, hTt, bitsT, E1a, E2a, F1a, F2a, out);
}